// Round 7
// baseline (9729.784 us; speedup 1.0000x reference)
//
#include <hip/hip_runtime.h>
#include <math.h>

#define VSZ 10000
#define HSZ 1024
#define BSZ 32
#define TSZ 128
#define BT  (BSZ*TSZ)      // 4096 rows
#define K2  (2*HSZ)        // 2048 (concat input width)

// ---------------------------------------------------------------- gather
__global__ void k_gather(const int* __restrict__ ids, const float* __restrict__ E,
                         float* __restrict__ x) {
  const int m = blockIdx.x;
  const int id = ids[m];
  const float4* s = (const float4*)(E + (size_t)id * HSZ);
  float4* d = (float4*)(x + (size_t)m * HSZ);
  d[threadIdx.x] = s[threadIdx.x];   // 256 thr * float4 = 1024 floats
}

// ---------------------------------------------------------------- GRU phase
// One launch = one [32, Kin=2048] @ [2048, nout] GEMM + activation epilogue.
// Multi-launch (one kernel per phase): stream ordering supplies the global
// sync + cross-XCD memory visibility that grid.sync() was suspected of
// failing to provide (round-4 output was exactly zeros => k_gru inert).
// 256 WGs x 256 threads. NCOLS columns per WG (8 gates, 4 cand).
template<int NCOLS, int MODE>  // MODE 0 = gates (sigmoid,r,u), 1 = cand (tanh,h-update)
__global__ __launch_bounds__(256)
void k_phase(const float* __restrict__ s1, const int s1s,   // k in [0,1024)
             const float* __restrict__ s2, const int s2s,   // k in [1024,2048)
             const float* __restrict__ W, const int ldw, const float* __restrict__ bias,
             float* __restrict__ hstate, float* __restrict__ rh, float* __restrict__ ub,
             float* __restrict__ hout_t)
{
  __shared__ float lds[16384];   // 64 KB: xh tile (9216 f) then reduction buffer
  const int tid = threadIdx.x;
  // XCD swizzle: 32 consecutive logical column-WGs land on the same XCD.
  const int wg = (blockIdx.x % 8) * 32 + blockIdx.x / 8;

  constexpr int JLN = NCOLS / 4;
  constexpr int KTN = 256 / (2 * JLN);   // 64 (gates) or 128 (cand)
  constexpr int KKC = 256 / KTN;         // 4 or 2
  const int jl = tid % JLN;
  const int bh = (tid / JLN) % 2;
  const int kt = tid / (2 * JLN);
  const int j0 = wg * NCOLS + jl * 4;

  float acc[16][4];
  #pragma unroll
  for (int b = 0; b < 16; ++b)
    #pragma unroll
    for (int u = 0; u < 4; ++u) acc[b][u] = 0.f;

  const int sb  = tid >> 3;   // staging: b row [0,32)
  const int skq = tid & 7;    // staging: k-octet

  for (int tau = 0; tau < 8; ++tau) {     // 8 k-tiles of 256
    __syncthreads();
    {   // stage xh[kl][b] into lds, layout [256][36]
      const float* src = (tau < 4) ? s1 : s2;
      const int ss = (tau < 4) ? s1s : s2s;
      const int kb = (tau & 3) * 256;
      #pragma unroll
      for (int i = 0; i < 8; ++i) {
        const int kl = (i * 8 + skq) * 4;
        float vv[4];
        *(float4*)vv = *(const float4*)(src + (size_t)sb * ss + kb + kl);
        #pragma unroll
        for (int c = 0; c < 4; ++c) lds[(kl + c) * 36 + sb] = vv[c];
      }
    }
    __syncthreads();
    #pragma unroll
    for (int kk = 0; kk < KKC; ++kk) {
      const int kl = kt + KTN * kk;
      const int kg = tau * 256 + kl;
      float wv[4];
      *(float4*)wv = *(const float4*)(W + (size_t)kg * ldw + j0);
      float xv[16];
      const float* xr = &lds[kl * 36 + bh * 16];
      *(float4*)&xv[0]  = *(const float4*)(xr + 0);
      *(float4*)&xv[4]  = *(const float4*)(xr + 4);
      *(float4*)&xv[8]  = *(const float4*)(xr + 8);
      *(float4*)&xv[12] = *(const float4*)(xr + 12);
      #pragma unroll
      for (int b = 0; b < 16; ++b)
        #pragma unroll
        for (int u = 0; u < 4; ++u)
          acc[b][u] = fmaf(xv[b], wv[u], acc[b][u]);
    }
  }

  // in-WG K reduction via LDS (swizzled slots, conflict-free)
  __syncthreads();
  #pragma unroll
  for (int b = 0; b < 16; ++b)
    #pragma unroll
    for (int u = 0; u < 4; ++u) {
      const int out = (bh * 16 + b) * NCOLS + jl * 4 + u;
      lds[out * KTN + ((kt + out) & (KTN - 1))] = acc[b][u];
    }
  __syncthreads();
  constexpr int OUTC = 32 * NCOLS;
  if (tid < OUTC) {
    float v = 0.f;
    #pragma unroll 8
    for (int k2 = 0; k2 < KTN; ++k2) v += lds[tid * KTN + ((k2 + tid) & (KTN - 1))];
    const int b  = tid / NCOLS;
    const int jc = tid % NCOLS;
    const int j  = wg * NCOLS + jc;
    if (MODE == 0) {
      const float g = 1.f / (1.f + expf(-(v + bias[j])));
      if (j < HSZ) rh[b * HSZ + j] = g * hstate[b * HSZ + j];   // r * h
      else         ub[b * HSZ + (j - HSZ)] = g;                 // u
    } else {
      const float c = tanhf(v + bias[j]);
      const float u = ub[b * HSZ + j];
      const float hold = hstate[b * HSZ + j];
      const float hn = u * hold + (1.f - u) * c;
      hstate[b * HSZ + j] = hn;
      if (hout_t) hout_t[(size_t)b * (TSZ * HSZ) + j] = hn;
    }
  }
}

// ---------------------------------------------------------------- projection
// C[4096,10000] = hout @ E^T + softmax_b. f32, 64x64 tile, 4x4 register block.
__global__ __launch_bounds__(256)
void k_proj(const float* __restrict__ A, const float* __restrict__ E,
            const float* __restrict__ sbias, float* __restrict__ C)
{
  __shared__ float At[32][68];
  __shared__ float Bt[32][68];
  const int bn = blockIdx.x * 64, bm = blockIdx.y * 64;
  const int tx = threadIdx.x & 15, ty = threadIdx.x >> 4;
  float acc[4][4];
  #pragma unroll
  for (int i = 0; i < 4; ++i)
    #pragma unroll
    for (int j = 0; j < 4; ++j) acc[i][j] = 0.f;

  for (int k0 = 0; k0 < HSZ; k0 += 32) {
    __syncthreads();
    #pragma unroll
    for (int i = 0; i < 2; ++i) {
      const int f4 = threadIdx.x + i * 256;
      const int r = f4 >> 3, kq = (f4 & 7) << 2;
      float av[4];
      *(float4*)av = *(const float4*)(A + (size_t)(bm + r) * HSZ + k0 + kq);
      #pragma unroll
      for (int c = 0; c < 4; ++c) At[kq + c][r] = av[c];
      const int vv = bn + r;
      float bv[4];
      *(float4*)bv = (vv < VSZ) ? *(const float4*)(E + (size_t)vv * HSZ + k0 + kq)
                                : make_float4(0.f, 0.f, 0.f, 0.f);
      #pragma unroll
      for (int c = 0; c < 4; ++c) Bt[kq + c][r] = bv[c];
    }
    __syncthreads();
    #pragma unroll
    for (int kk = 0; kk < 32; ++kk) {
      float a[4], b[4];
      *(float4*)a = *(const float4*)&At[kk][ty * 4];
      *(float4*)b = *(const float4*)&Bt[kk][tx * 4];
      #pragma unroll
      for (int i = 0; i < 4; ++i)
        #pragma unroll
        for (int j = 0; j < 4; ++j)
          acc[i][j] = fmaf(a[i], b[j], acc[i][j]);
    }
  }
  #pragma unroll
  for (int i = 0; i < 4; ++i) {
    const int m = bm + ty * 4 + i;
    #pragma unroll
    for (int j = 0; j < 4; ++j) {
      const int col = bn + tx * 4 + j;
      if (col < VSZ) C[(size_t)m * VSZ + col] = acc[i][j] + sbias[col];
    }
  }
}

// ---------------------------------------------------------------- launch
extern "C" void kernel_launch(void* const* d_in, const int* in_sizes, int n_in,
                              void* d_out, int out_size, void* d_ws, size_t ws_size,
                              hipStream_t stream) {
  const int*   ids = (const int*)d_in[0];
  const float* E   = (const float*)d_in[1];
  const float* Wg0 = (const float*)d_in[2];
  const float* bg0 = (const float*)d_in[3];
  const float* Wc0 = (const float*)d_in[4];
  const float* bc0 = (const float*)d_in[5];
  const float* Wg1 = (const float*)d_in[6];
  const float* bg1 = (const float*)d_in[7];
  const float* Wc1 = (const float*)d_in[8];
  const float* bc1 = (const float*)d_in[9];
  const float* sb  = (const float*)d_in[10];
  float* out = (float*)d_out;

  float* ws   = (float*)d_ws;
  float* x    = ws;                          // 4096*1024
  float* hout = x + (size_t)BT * HSZ;        // 4096*1024
  float* h0   = hout + (size_t)BT * HSZ;     // 32*1024
  float* h1   = h0 + BSZ * HSZ;              // 32*1024 (contiguous with h0)
  float* rh   = h1 + BSZ * HSZ;              // 32*1024
  float* ub   = rh + BSZ * HSZ;              // 32*1024

  k_gather<<<dim3(BT), dim3(256), 0, stream>>>(ids, E, x);
  hipMemsetAsync(h0, 0, 2 * BSZ * HSZ * sizeof(float), stream);  // h0, h1 = 0

  for (int t = 0; t < TSZ; ++t) {
    const float* xt = x + (size_t)t * HSZ;   // per-b row stride = TSZ*HSZ
    // P1: gates layer 0: sigmoid([x_t ; h0] @ Wg0 + bg0) -> rh, ub
    k_phase<8, 0><<<dim3(256), dim3(256), 0, stream>>>(xt, TSZ * HSZ, h0, HSZ, Wg0, K2, bg0, h0, rh, ub, nullptr);
    // P2: cand layer 0: tanh([x_t ; r*h0] @ Wc0 + bc0); h0 = u*h0 + (1-u)*c
    k_phase<4, 1><<<dim3(256), dim3(256), 0, stream>>>(xt, TSZ * HSZ, rh, HSZ, Wc0, HSZ, bc0, h0, rh, ub, nullptr);
    // P3: gates layer 1 (input = updated h0)
    k_phase<8, 0><<<dim3(256), dim3(256), 0, stream>>>(h0, HSZ, h1, HSZ, Wg1, K2, bg1, h1, rh, ub, nullptr);
    // P4: cand layer 1; h1 update; emit h1 -> hout[b*T + t]
    k_phase<4, 1><<<dim3(256), dim3(256), 0, stream>>>(h0, HSZ, rh, HSZ, Wc1, HSZ, bc1, h1, rh, ub, hout + (size_t)t * HSZ);
  }

  k_proj<<<dim3((VSZ + 63) / 64, BT / 64), dim3(256), 0, stream>>>(hout, E, sb, out);
}